// Round 1
// baseline (178.433 us; speedup 1.0000x reference)
//
#include <hip/hip_runtime.h>
#include <hip/hip_bf16.h>
#include <math.h>

#define D_MODEL 1024
#define NHEAD 16
#define DHEAD 64
#define SEQ 2048
#define BATCH 2
#define MTOT (BATCH * SEQ)  // 4096

typedef __attribute__((ext_vector_type(8))) short bf16x8;   // 4 VGPRs = MFMA A/B frag
typedef __attribute__((ext_vector_type(4))) float f32x4;    // MFMA C/D frag

static __device__ __forceinline__ ushort f2b(float x) {
  __hip_bfloat16 h = __float2bfloat16(x);
  union { __hip_bfloat16 h; ushort u; } cv; cv.h = h; return cv.u;
}

// async global->LDS, 16B per lane (m97). LDS dest = wave-uniform base + lane*16.
#define GLLDS16(gp, lp)                                                     \
  __builtin_amdgcn_global_load_lds(                                         \
      (const __attribute__((address_space(1))) unsigned int*)(gp),          \
      (__attribute__((address_space(3))) unsigned int*)(lp), 16, 0, 0)

// 0.125 (1/sqrt(Dh)) * log2(e): folded into Q at projection; flash exp2's raw scores
#define QSCALE 0.18033688011112042f

#define MFMA16(a_, b_, c_) \
  __builtin_amdgcn_mfma_f32_16x16x32_bf16(a_, b_, c_, 0, 0, 0)
#define SBAR() __builtin_amdgcn_s_barrier()
#define WAIT_LGKM0                                         \
  do {                                                     \
    asm volatile("s_waitcnt lgkmcnt(0)" ::: "memory");     \
    __builtin_amdgcn_sched_barrier(0);                     \
  } while (0)
#define WAIT_VM6                                           \
  do {                                                     \
    asm volatile("s_waitcnt vmcnt(6)" ::: "memory");       \
    __builtin_amdgcn_sched_barrier(0);                     \
  } while (0)
#define WAIT_VM0                                           \
  do {                                                     \
    asm volatile("s_waitcnt vmcnt(0)" ::: "memory");       \
    __builtin_amdgcn_sched_barrier(0);                     \
  } while (0)

// ---------------------------------------------------------------------------
// prep: fp32->bf16 for X + 4 weights, plus RoPE cos/sin table.
// ---------------------------------------------------------------------------
__global__ __launch_bounds__(256)
void prep(const float* __restrict__ X, const float* __restrict__ Wq,
          const float* __restrict__ Wk, const float* __restrict__ Wv,
          const float* __restrict__ Wo, ushort* __restrict__ Xb,
          ushort* __restrict__ Wqb, ushort* __restrict__ Wkb,
          ushort* __restrict__ Wvb, ushort* __restrict__ Wob,
          float2* __restrict__ tbl) {
  int bid = blockIdx.x;
  if (bid >= 8192) {  // rope table: idx = s*32 + i
    int idx = (bid - 8192) * 256 + threadIdx.x;
    int s = idx >> 5, i = idx & 31;
    float inv = exp2f((float)i * -0.4152410118609203f);  // 10000^(-i/32)
    float sn, cs;
    sincosf((float)s * inv, &sn, &cs);
    tbl[idx] = make_float2(cs, sn);
    return;
  }
  const float* in;
  ushort* out;
  int i;
  if (bid < 4096) {
    in = X; out = Xb; i = bid * 256 + threadIdx.x;
  } else {
    int ws = (bid - 4096) >> 10;
    in = (ws == 0) ? Wq : (ws == 1) ? Wk : (ws == 2) ? Wv : Wo;
    out = (ws == 0) ? Wqb : (ws == 1) ? Wkb : (ws == 2) ? Wvb : Wob;
    i = ((bid - 4096) & 1023) * 256 + threadIdx.x;
  }
  float4 v = ((const float4*)in)[i];
  ushort4 o;
  o.x = f2b(v.x); o.y = f2b(v.y); o.z = f2b(v.z); o.w = f2b(v.w);
  ((ushort4*)out)[i] = o;
}

// ---------------------------------------------------------------------------
// QKV projection: 256x256-tile / BK=64 / 8-wave / 8-phase counted-vmcnt GEMM
// (m201 template, T2+T3+T4+T5). 512 thr = 8 waves (2M x 4N); per-wave output
// 128x64 split as rows {wy*64..+64} u {128+wy*64..}, cols {wx*32..} u
// {128+wx*32..} so each half-tile (A-lo/A-hi/B-lo/B-hi = 128 rows) is
// consumed by exactly one phase: P0 reads A-lo+B-lo, P1 B-hi, P2 A-hi.
// Stage schedule (1 half-tile/phase, into the region just freed):
//   P0: A-hi(u+1)   P1: A-lo(u+2)   P2: B-lo(u+2)   P3: B-hi(u+2)
// vmcnt(6) once per K-tile at end of P3 (3 half-tiles always in flight),
// before the closing barrier => cross-wave landing guarantee for tile u+1.
// LDS 128 KiB (2 dbuf x 2 half x 128x64 x 2 ops), chunk-XOR swizzled
// (slot = chunk ^ (row&7)); inverse XOR pre-applied to global source since
// global_load_lds writes linearly. Epilogue: fused RoPE (Q/K, Q pre-scaled)
// / V transposed + key-permuted, identical semantics to the 128^2 kernel.
// ---------------------------------------------------------------------------
__global__ __launch_bounds__(512, 2)
void gemm256_qkv(const ushort* __restrict__ A,
                 const ushort* __restrict__ W0, const ushort* __restrict__ W1,
                 const ushort* __restrict__ W2,
                 const float2* __restrict__ tbl,
                 ushort* __restrict__ o0, ushort* __restrict__ o1,
                 ushort* __restrict__ o2) {
  __shared__ ushort sm[65536];  // 128 KiB. A: [0,32768) B: [32768,65536)
  const int tid = threadIdx.x;
  const int lane = tid & 63;
  const int w = tid >> 6;
  const int wy = w >> 2, wx = w & 3;
  const int quad = lane >> 4, l15 = lane & 15;

  // XCD-aware bijective block remap: nwg = 192 = 8 XCDs * 24
  int flat = blockIdx.x + (blockIdx.y << 2) + (blockIdx.z << 6);
  int nf = (flat & 7) * 24 + (flat >> 3);
  const int z = nf >> 6;
  const int m0 = ((nf >> 2) & 15) << 8;
  const int n0 = (nf & 3) << 8;

  const ushort* W = (z == 0) ? W0 : (z == 1) ? W1 : W2;
  ushort* outB = (z == 0) ? o0 : (z == 1) ? o1 : o2;

  // staging constants: thread owns row sr of each 64-row call, chunk slot
  // tid&7; global chunk pre-swizzled so LDS slot s holds chunk s^(row&7).
  const int sr = tid >> 3;                // 0..63
  const int scx = (tid & 7) ^ (sr & 7);   // pre-swizzled global chunk
  const ushort* Ag = A + (size_t)(m0 + sr) * D_MODEL + scx * 8;
  const ushort* Wg = W + (size_t)(n0 + sr) * D_MODEL + scx * 8;

#define STG_A(u, h)                                                         \
  do {                                                                      \
    GLLDS16(Ag + (size_t)((h) * 128) * D_MODEL + (u) * 64,                  \
            &sm[((u) & 1) * 16384 + (h) * 8192 + tid * 8]);                 \
    GLLDS16(Ag + (size_t)((h) * 128 + 64) * D_MODEL + (u) * 64,             \
            &sm[((u) & 1) * 16384 + (h) * 8192 + 4096 + tid * 8]);          \
  } while (0)
#define STG_B(u, h)                                                         \
  do {                                                                      \
    GLLDS16(Wg + (size_t)((h) * 128) * D_MODEL + (u) * 64,                  \
            &sm[32768 + ((u) & 1) * 16384 + (h) * 8192 + tid * 8]);         \
    GLLDS16(Wg + (size_t)((h) * 128 + 64) * D_MODEL + (u) * 64,             \
            &sm[32768 + ((u) & 1) * 16384 + (h) * 8192 + 4096 + tid * 8]);  \
  } while (0)

  // reader: frag (row16=l15, chunk=4*kk+quad) at slot (4kk+quad)^(l15&7);
  // kk=1 is addr ^ 32 (ushorts). 8 lanes per bank-quad -> conflict-free.
  const int slot0 = quad ^ (l15 & 7);
  const int aoff = (wy * 64 + l15) * 64 + slot0 * 8;  // within A half-region
  const int boff = (wx * 32 + l15) * 64 + slot0 * 8;  // within B half-region

  f32x4 acc[8][4];
#pragma unroll
  for (int i = 0; i < 8; ++i)
#pragma unroll
    for (int j = 0; j < 4; ++j) acc[i][j] = (f32x4){0.f, 0.f, 0.f, 0.f};

  bf16x8 a[4][2], bl[2][2], bh[2][2];

  // prologue: tile0 complete + tile1 first 3 halves (A-hi(1) lands at g0.P0)
  STG_A(0, 0); STG_B(0, 0); STG_B(0, 1); STG_A(0, 1);
  STG_A(1, 0); STG_B(1, 0); STG_B(1, 1);
  WAIT_VM6;   // tile 0 fully landed; 3 halves of tile 1 in flight
  SBAR();

  for (int u = 0; u < 16; ++u) {
    const ushort* As_ = &sm[(u & 1) * 16384];
    const ushort* Bs_ = &sm[32768 + (u & 1) * 16384];

    // ------- P0: ds_read A-lo + B-lo; stage A-hi(u+1); MFMA (lo,lo)
#pragma unroll
    for (int i = 0; i < 4; ++i) {
      a[i][0] = *(const bf16x8*)&As_[aoff + i * 1024];
      a[i][1] = *(const bf16x8*)&As_[(aoff ^ 32) + i * 1024];
    }
#pragma unroll
    for (int j = 0; j < 2; ++j) {
      bl[j][0] = *(const bf16x8*)&Bs_[boff + j * 1024];
      bl[j][1] = *(const bf16x8*)&Bs_[(boff ^ 32) + j * 1024];
    }
    if (u < 15) STG_A(u + 1, 1);
    SBAR();
    WAIT_LGKM0;
    __builtin_amdgcn_s_setprio(1);
#pragma unroll
    for (int i = 0; i < 4; ++i)
#pragma unroll
      for (int j = 0; j < 2; ++j) {
        acc[i][j] = MFMA16(a[i][0], bl[j][0], acc[i][j]);
        acc[i][j] = MFMA16(a[i][1], bl[j][1], acc[i][j]);
      }
    __builtin_amdgcn_s_setprio(0);
    SBAR();

    // ------- P1: ds_read B-hi; stage A-lo(u+2); MFMA (lo,hi)
#pragma unroll
    for (int j = 0; j < 2; ++j) {
      bh[j][0] = *(const bf16x8*)&Bs_[8192 + boff + j * 1024];
      bh[j][1] = *(const bf16x8*)&Bs_[8192 + (boff ^ 32) + j * 1024];
    }
    if (u < 14) STG_A(u + 2, 0);
    SBAR();
    WAIT_LGKM0;
    __builtin_amdgcn_s_setprio(1);
#pragma unroll
    for (int i = 0; i < 4; ++i)
#pragma unroll
      for (int j = 0; j < 2; ++j) {
        acc[i][2 + j] = MFMA16(a[i][0], bh[j][0], acc[i][2 + j]);
        acc[i][2 + j] = MFMA16(a[i][1], bh[j][1], acc[i][2 + j]);
      }
    __builtin_amdgcn_s_setprio(0);
    SBAR();

    // ------- P2: ds_read A-hi; stage B-lo(u+2); MFMA (hi,lo)
#pragma unroll
    for (int i = 0; i < 4; ++i) {
      a[i][0] = *(const bf16x8*)&As_[8192 + aoff + i * 1024];
      a[i][1] = *(const bf16x8*)&As_[8192 + (aoff ^ 32) + i * 1024];
    }
    if (u < 14) STG_B(u + 2, 0);
    SBAR();
    WAIT_LGKM0;
    __builtin_amdgcn_s_setprio(1);
#pragma unroll
    for (int i = 0; i < 4; ++i)
#pragma unroll
      for (int j = 0; j < 2; ++j) {
        acc[4 + i][j] = MFMA16(a[i][0], bl[j][0], acc[4 + i][j]);
        acc[4 + i][j] = MFMA16(a[i][1], bl[j][1], acc[4 + i][j]);
      }
    __builtin_amdgcn_s_setprio(0);
    SBAR();

    // ------- P3: stage B-hi(u+2); MFMA (hi,hi); counted vmcnt; barrier
    if (u < 14) STG_B(u + 2, 1);
    SBAR();
    __builtin_amdgcn_s_setprio(1);
#pragma unroll
    for (int i = 0; i < 4; ++i)
#pragma unroll
      for (int j = 0; j < 2; ++j) {
        acc[4 + i][2 + j] = MFMA16(a[i][0], bh[j][0], acc[4 + i][2 + j]);
        acc[4 + i][2 + j] = MFMA16(a[i][1], bh[j][1], acc[4 + i][2 + j]);
      }
    __builtin_amdgcn_s_setprio(0);
    // per-wave: tile u+1 fully landed, <=3 halves (tile u+2) in flight;
    // the closing barrier then makes it a cross-wave guarantee.
    if (u < 14) { WAIT_VM6; } else { WAIT_VM0; }
    SBAR();
  }

  // ---- epilogue (same semantics as 128^2 kernel, new row/col mapping)
  const float qsc = (z == 0) ? QSCALE : 1.0f;
#pragma unroll
  for (int mt = 0; mt < 8; ++mt) {
    int gm = m0 + ((mt >> 2) << 7) + wy * 64 + (mt & 3) * 16 + quad * 4;
    int b = gm >> 11, s_base = gm & (SEQ - 1);
#pragma unroll
    for (int nt = 0; nt < 4; ++nt) {
      int n = n0 + ((nt >> 1) << 7) + wx * 32 + (nt & 1) * 16 + l15;
      int h = n >> 6, dh = n & 63;
      if (z == 2) {  // V: transposed + key-permuted columns
        int p_base = (s_base & ~31) | (((s_base >> 2) & 3) << 3) |
                     (((s_base >> 4) & 1) << 2);
        ushort4 o;
        o.x = f2b(acc[mt][nt][0]); o.y = f2b(acc[mt][nt][1]);
        o.z = f2b(acc[mt][nt][2]); o.w = f2b(acc[mt][nt][3]);
        *(ushort4*)&outB[((size_t)(b * NHEAD + h) * DHEAD + dh) * SEQ + p_base] = o;
      } else {       // Q/K: RoPE via table, pair partner via lane shuffle
        int fi = dh >> 1;          // pair-uniform freq index
        bool evn = !(dh & 1);
#pragma unroll
        for (int r = 0; r < 4; ++r) {
          float v = acc[mt][nt][r];
          float pv = __shfl_xor(v, 1);
          float2 csn = tbl[(s_base + r) * 32 + fi];
          v = v * csn.x + (evn ? -pv * csn.y : pv * csn.y);
          v *= qsc;
          outB[(((size_t)(b * NHEAD + h)) * SEQ + s_base + r) * DHEAD + dh] = f2b(v);
        }
      }
    }
  }
}

// ---------------------------------------------------------------------------
// bf16 MFMA GEMM (m97 staging, 128^2): retained for the output projection
// (mode 0) where a 256^2 grid would launch only 64 workgroups (25% CU fill).
// ---------------------------------------------------------------------------
__global__ __launch_bounds__(256)
void gemm_bf16(const ushort* __restrict__ A,
               const ushort* __restrict__ W0, const ushort* __restrict__ W1,
               const ushort* __restrict__ W2,
               const float2* __restrict__ tbl,
               float* __restrict__ outF,
               ushort* __restrict__ o0, ushort* __restrict__ o1,
               ushort* __restrict__ o2, int mode) {
  __shared__ ushort As[128 * 32];
  __shared__ ushort Bs[128 * 32];
  const int tid = threadIdx.x;
  const int lane = tid & 63;
  const int w = tid >> 6;
  const int quad = lane >> 4, l15 = lane & 15;
  const int wy = w >> 1, wx = w & 1;
  const int m0 = blockIdx.y * 128, n0 = blockIdx.x * 128;
  const int z = blockIdx.z;
  const ushort* W = (z == 0) ? W0 : (z == 1) ? W1 : W2;
  ushort* outB = (z == 0) ? o0 : (z == 1) ? o1 : o2;

  const int r0 = tid >> 2, c0 = tid & 3;
  const int gc = c0 ^ (((r0 >> 2) ^ r0) & 3);  // f(r0) == f(r0+64)
  const ushort* Ag0 = A + (size_t)(m0 + r0) * D_MODEL + gc * 8;
  const ushort* Ag1 = A + (size_t)(m0 + r0 + 64) * D_MODEL + gc * 8;
  const ushort* Wg0 = W + (size_t)(n0 + r0) * D_MODEL + gc * 8;
  const ushort* Wg1 = W + (size_t)(n0 + r0 + 64) * D_MODEL + gc * 8;

  const int sw = (quad ^ (l15 >> 2) ^ l15) & 3;

  f32x4 acc[4][4];
#pragma unroll
  for (int i = 0; i < 4; ++i)
#pragma unroll
    for (int j = 0; j < 4; ++j) acc[i][j] = (f32x4){0.f, 0.f, 0.f, 0.f};

  for (int kt = 0; kt < D_MODEL / 32; ++kt) {
    if (kt) __syncthreads();
    GLLDS16(Ag0 + kt * 32, &As[(size_t)tid * 8]);
    GLLDS16(Ag1 + kt * 32, &As[(size_t)(tid + 256) * 8]);
    GLLDS16(Wg0 + kt * 32, &Bs[(size_t)tid * 8]);
    GLLDS16(Wg1 + kt * 32, &Bs[(size_t)(tid + 256) * 8]);
    __syncthreads();  // compiler drains vmcnt before barrier

    bf16x8 af[4], bfr[4];
#pragma unroll
    for (int mt = 0; mt < 4; ++mt) {
      int row = wy * 64 + mt * 16 + l15;
      af[mt] = *(const bf16x8*)&As[(row * 4 + sw) * 8];
    }
#pragma unroll
    for (int nt = 0; nt < 4; ++nt) {
      int row = wx * 64 + nt * 16 + l15;
      bfr[nt] = *(const bf16x8*)&Bs[(row * 4 + sw) * 8];
    }
#pragma unroll
    for (int mt = 0; mt < 4; ++mt)
#pragma unroll
      for (int nt = 0; nt < 4; ++nt)
        acc[mt][nt] = __builtin_amdgcn_mfma_f32_16x16x32_bf16(
            af[mt], bfr[nt], acc[mt][nt], 0, 0, 0);
  }

  // ---- epilogue. C/D: row = quad*4+r, col = l15 per 16x16 tile.
  const float qsc = (z == 0) ? QSCALE : 1.0f;
#pragma unroll
  for (int mt = 0; mt < 4; ++mt) {
    int m_base = m0 + wy * 64 + mt * 16 + quad * 4;
    int b = m_base >> 11, s_base = m_base & (SEQ - 1);
#pragma unroll
    for (int nt = 0; nt < 4; ++nt) {
      int n = n0 + wx * 64 + nt * 16 + l15;
      if (mode == 0) {
#pragma unroll
        for (int r = 0; r < 4; ++r)
          outF[(size_t)(m_base + r) * D_MODEL + n] = acc[mt][nt][r];
      } else {
        int h = n >> 6, dh = n & 63;
        if (z == 2) {  // V: transposed + key-permuted columns (see header)
          int p_base = (s_base & ~31) | (((s_base >> 2) & 3) << 3) |
                       (((s_base >> 4) & 1) << 2);
          ushort4 o;
          o.x = f2b(acc[mt][nt][0]); o.y = f2b(acc[mt][nt][1]);
          o.z = f2b(acc[mt][nt][2]); o.w = f2b(acc[mt][nt][3]);
          *(ushort4*)&outB[((size_t)(b * NHEAD + h) * DHEAD + dh) * SEQ + p_base] = o;
        } else {       // Q/K: RoPE via table, pair partner via lane shuffle
          int i = nt * 8 + (l15 >> 1);   // freq index, pair-uniform
          bool evn = !(l15 & 1);
#pragma unroll
          for (int r = 0; r < 4; ++r) {
            float v = acc[mt][nt][r];
            float pv = __shfl_xor(v, 1);
            float2 csn = tbl[(s_base + r) * 32 + i];
            v = v * csn.x + (evn ? -pv * csn.y : pv * csn.y);
            v *= qsc;
            outB[(((size_t)(b * NHEAD + h)) * SEQ + s_base + r) * DHEAD + dh] = f2b(v);
          }
        }
      }
    }
  }
}

// ---------------------------------------------------------------------------
// bf16 MFMA causal flash attention -- S^T operand-swap form (P LDS round-trip
// ELIMINATED). See previous-round header; unchanged this round.
// ---------------------------------------------------------------------------
__global__ __launch_bounds__(256)
void flash_mfma(const ushort* __restrict__ Q, const ushort* __restrict__ K,
                const ushort* __restrict__ Vt, ushort* __restrict__ O) {
  __shared__ ushort Ks[64 * 64];     // [key][dh], chunk-swizzled
  __shared__ ushort Vs[64 * 64];     // [dh][keypos], chunk-swizzled
  const int tid = threadIdx.x;
  const int lane = tid & 63, w = tid >> 6;
  const int quad = lane >> 4, l15 = lane & 15;
  const int h = blockIdx.y, b = blockIdx.z;
  const int qt = (h >= 8) ? (31 - blockIdx.x) : blockIdx.x;
  const int bh = b * NHEAD + h;

  // Q as B-operand (B frag layout == A frag layout): lane n=l15=qrow
  const int qrow = qt * 64 + w * 16 + l15;
  const ushort* Qrow = Q + ((size_t)bh * SEQ + qrow) * 64;
  bf16x8 aq0 = *(const bf16x8*)(Qrow + quad * 8);
  bf16x8 aq1 = *(const bf16x8*)(Qrow + 32 + quad * 8);

  // staging: thread owns rows rl and rl+32, LDS slot tid&7, global chunk XOR'd
  const int rl = tid >> 3;
  const int gsc = (tid & 7) ^ (rl & 7);  // (rl+32)&7 == rl&7
  const ushort* Kg0 = K + ((size_t)bh * SEQ + rl) * 64 + gsc * 8;
  const ushort* Kg1 = Kg0 + (size_t)32 * 64;
  const ushort* Vg0 = Vt + ((size_t)bh * 64 + rl) * SEQ + gsc * 8;
  const ushort* Vg1 = Vg0 + (size_t)32 * SEQ;

  // reader chunk slots (slot quad^(r&7) holds chunk quad; frag rows r&7==l15&7)
  const int sA = (quad ^ (l15 & 7)) * 8;  // dh/keypos 0..31
  const int sB = sA ^ 32;                 // dh/keypos 32..63

  float rsl = 0.f;       // per-lane row sum (lane's qrow)
  f32x4 accO[4];         // O^T dh-tiles: row=dh quad*4+r, col=l15=qrow
#pragma unroll
  for (int nt = 0; nt < 4; ++nt) accO[nt] = (f32x4){0.f, 0.f, 0.f, 0.f};

  float4 pk0 = *(const float4*)(Kg0);
  float4 pk1 = *(const float4*)(Kg1);
  float4 pv0 = *(const float4*)(Vg0);
  float4 pv1 = *(const float4*)(Vg1);

  for (int kt = 0; kt <= qt; ++kt) {
    __syncthreads();  // prior iter's LDS reads complete
    *(float4*)&Ks[tid * 8]        = pk0;
    *(float4*)&Ks[2048 + tid * 8] = pk1;
    *(float4*)&Vs[tid * 8]        = pv0;
    *(float4*)&Vs[2048 + tid * 8] = pv1;
    __syncthreads();
    if (kt < qt) {  // prefetch kt+1 into registers; overlaps all compute below
      pk0 = *(const float4*)(Kg0 + (size_t)(kt + 1) * 64 * 64);
      pk1 = *(const float4*)(Kg1 + (size_t)(kt + 1) * 64 * 64);
      pv0 = *(const float4*)(Vg0 + (kt + 1) * 64);
      pv1 = *(const float4*)(Vg1 + (kt + 1) * 64);
    }

    // ---- S^T = K . Q^T : C-tile nt holds keys nt*16+quad*4+r, qrow=l15
    f32x4 sc[4];
#pragma unroll
    for (int nt = 0; nt < 4; ++nt) {
      const ushort* kr = &Ks[(nt * 16 + l15) * 64];
      bf16x8 bk0 = *(const bf16x8*)(kr + sA);
      bf16x8 bk1 = *(const bf16x8*)(kr + sB);
      f32x4 zz = (f32x4){0.f, 0.f, 0.f, 0.f};
      zz = __builtin_amdgcn_mfma_f32_16x16x32_bf16(bk0, aq0, zz, 0, 0, 0);
      zz = __builtin_amdgcn_mfma_f32_16x16x32_bf16(bk1, aq1, zz, 0, 0, 0);
      sc[nt] = zz;
    }

    // ---- exp2 + causal mask + row-sum + pack P^T B-frags in registers
    const bool diag = (kt == qt);
    uint pk[8];
#pragma unroll
    for (int nt = 0; nt < 4; ++nt) {
      int kbase = kt * 64 + nt * 16 + quad * 4;
      ushort us[4];
#pragma unroll
      for (int r = 0; r < 4; ++r) {
        float p = __builtin_amdgcn_exp2f(sc[nt][r]);
        if (diag && kbase + r > qrow) p = 0.f;
        rsl += p;
        us[r] = f2b(p);
      }
      pk[nt * 2]     = (uint)us[0] | ((uint)us[1] << 16);
      pk[nt * 2 + 1] = (uint)us[2] | ((uint)us[3] << 16);
    }
    union { uint u[4]; bf16x8 v; } B0, B1;
    B0.u[0] = pk[0]; B0.u[1] = pk[1]; B0.u[2] = pk[2]; B0.u[3] = pk[3];
    B1.u[0] = pk[4]; B1.u[1] = pk[5]; B1.u[2] = pk[6]; B1.u[3] = pk[7];

    // ---- O^T += V^T . P^T  (A from LDS, B straight from registers)
#pragma unroll
    for (int nt = 0; nt < 4; ++nt) {
      const ushort* vr = &Vs[(nt * 16 + l15) * 64];
      bf16x8 av0 = *(const bf16x8*)(vr + sA);
      bf16x8 av1 = *(const bf16x8*)(vr + sB);
      accO[nt] = __builtin_amdgcn_mfma_f32_16x16x32_bf16(av0, B0.v, accO[nt], 0, 0, 0);
      accO[nt] = __builtin_amdgcn_mfma_f32_16x16x32_bf16(av1, B1.v, accO[nt], 0, 0, 0);
    }
  }

  // ---- row-sum reduction across the 4 quads (lane's qrow fixed = l15)
  rsl += __shfl_xor(rsl, 16);
  rsl += __shfl_xor(rsl, 32);
  float invl = 1.f / rsl;

  // ---- epilogue: attn_out bf16, (B,S,H*Dh); lane writes 4 ushort4 runs
  size_t base = ((size_t)(b * SEQ + qrow)) * D_MODEL + h * 64;
#pragma unroll
  for (int nt = 0; nt < 4; ++nt) {
    ushort4 o;
    o.x = f2b(accO[nt][0] * invl);
    o.y = f2b(accO[nt][1] * invl);
    o.z = f2b(accO[nt][2] * invl);
    o.w = f2b(accO[nt][3] * invl);
    *(ushort4*)&O[base + nt * 16 + quad * 4] = o;
  }
}

// ---------------------------------------------------------------------------
extern "C" void kernel_launch(void* const* d_in, const int* in_sizes, int n_in,
                              void* d_out, int out_size, void* d_ws, size_t ws_size,
                              hipStream_t stream) {
  const float* X  = (const float*)d_in[0];
  const float* Wq = (const float*)d_in[1];
  const float* Wk = (const float*)d_in[2];
  const float* Wv = (const float*)d_in[3];
  const float* Wo = (const float*)d_in[4];
  float* out = (float*)d_out;

  ushort* Xb  = (ushort*)d_ws;
  ushort* Wqb = Xb  + (size_t)MTOT * D_MODEL;
  ushort* Wkb = Wqb + (size_t)D_MODEL * D_MODEL;
  ushort* Wvb = Wkb + (size_t)D_MODEL * D_MODEL;
  ushort* Wob = Wvb + (size_t)D_MODEL * D_MODEL;
  ushort* Qw  = Wob + (size_t)D_MODEL * D_MODEL;
  ushort* Kw  = Qw  + (size_t)MTOT * D_MODEL;
  ushort* Vtw = Kw  + (size_t)MTOT * D_MODEL;  // (B,H,Dh,S) key-permuted
  ushort* At  = Vtw + (size_t)MTOT * D_MODEL;
  float2* tbl = (float2*)(At + (size_t)MTOT * D_MODEL);  // 512 KB

  prep<<<8448, 256, 0, stream>>>(X, Wq, Wk, Wv, Wo, Xb, Wqb, Wkb, Wvb, Wob, tbl);

  // QKV projection: 256^2 8-phase kernel; RoPE fused on Q/K, V transposed+permuted
  gemm256_qkv<<<dim3(D_MODEL / 256, MTOT / 256, 3), 512, 0, stream>>>(
      Xb, Wqb, Wkb, Wvb, tbl, Qw, Kw, Vtw);

  flash_mfma<<<dim3(SEQ / 64, NHEAD, BATCH), 256, 0, stream>>>(Qw, Kw, Vtw, At);

  gemm_bf16<<<dim3(D_MODEL / 128, MTOT / 128, 1), 256, 0, stream>>>(
      At, Wob, nullptr, nullptr, tbl, out, nullptr, nullptr, nullptr, 0);
}